// Round 2
// baseline (1586.629 us; speedup 1.0000x reference)
//
#include <hip/hip_runtime.h>
#include <hip/hip_bf16.h>

#define NN 2000
#define BB 32
#define FF 32
#define LL 10

// ---------------------------------------------------------------------------
// K1/K3: out(rows,32) = x(rows,32) @ w(32,32)
// lanes 0-31 share a row -> x loads broadcast; w row loads coalesced across f.
// ---------------------------------------------------------------------------
__global__ void small_mm(const float* __restrict__ x, const float* __restrict__ w,
                         float* __restrict__ out, int rows) {
    int t = blockIdx.x * blockDim.x + threadIdx.x;
    if (t >= rows * 32) return;
    int f = t & 31;
    int r = t >> 5;
    const float* xr = x + (size_t)r * 32;
    float acc = 0.f;
#pragma unroll
    for (int k = 0; k < 32; ++k) acc += xr[k] * w[k * 32 + f];
    out[t] = acc;
}

// ---------------------------------------------------------------------------
// gcn_partial: partial[c][b][i][f] = sum_{j in chunk c} adj[b][i][j]*h[b][j][f]
// One thread per output row i, j split across blockIdx.z (chunk multiple of 4
// -> 16B-aligned float4 stream). h pointer is block-uniform -> scalar-cache
// broadcast loads; adj is a lane-private contiguous float4 stream.
// ---------------------------------------------------------------------------
__global__ void gcn_partial(const float* __restrict__ adj, const float* __restrict__ h,
                            float* __restrict__ partial, int chunk) {
    const int c = blockIdx.z;
    const int b = blockIdx.y;
    const int i = blockIdx.x * blockDim.x + threadIdx.x;
    if (i >= NN) return;

    const float* __restrict__ arow = adj + ((size_t)b * NN + i) * NN + (size_t)c * chunk;
    const float* __restrict__ hb   = h + ((size_t)b * NN + (size_t)c * chunk) * FF;

    float acc[FF];
#pragma unroll
    for (int f = 0; f < FF; ++f) acc[f] = 0.f;

    const int iters = chunk >> 2;
    for (int jj = 0; jj < iters; ++jj) {
        const float4 a = reinterpret_cast<const float4*>(arow)[jj];
        const float* __restrict__ h0 = hb + (size_t)jj * 4 * FF;
#pragma unroll
        for (int f = 0; f < FF; ++f) acc[f] += a.x * h0[f];
#pragma unroll
        for (int f = 0; f < FF; ++f) acc[f] += a.y * h0[FF + f];
#pragma unroll
        for (int f = 0; f < FF; ++f) acc[f] += a.z * h0[2 * FF + f];
#pragma unroll
        for (int f = 0; f < FF; ++f) acc[f] += a.w * h0[3 * FF + f];
    }

    float* __restrict__ prow = partial + ((size_t)c * BB * NN + (size_t)b * NN + i) * FF;
#pragma unroll
    for (int f = 0; f < FF; ++f) prow[f] = acc[f];
}

// ---------------------------------------------------------------------------
// reduce_relu: y[t] = relu(sum_c partial[c][t])   (layer 1 epilogue)
// fully coalesced; grid exact (BB*NN*FF/256 = 8000 blocks)
// ---------------------------------------------------------------------------
__global__ void reduce_relu(const float* __restrict__ partial, float* __restrict__ y, int jc) {
    const size_t t = (size_t)blockIdx.x * 256 + threadIdx.x;
    const size_t stride = (size_t)BB * NN * FF;
    float s = 0.f;
    for (int c = 0; c < jc; ++c) s += partial[c * stride + t];
    y[t] = fmaxf(s, 0.f);
}

// ---------------------------------------------------------------------------
// reduce_relu_sum: rowsum[r] = sum_f relu(sum_c partial[c][r][f])  (layer 2)
// lanes {32k..32k+31} hold f=0..31 of one row -> shfl_xor reduce within 32.
// ---------------------------------------------------------------------------
__global__ void reduce_relu_sum(const float* __restrict__ partial, float* __restrict__ rowsum, int jc) {
    const size_t t = (size_t)blockIdx.x * 256 + threadIdx.x;
    const size_t stride = (size_t)BB * NN * FF;
    float s = 0.f;
    for (int c = 0; c < jc; ++c) s += partial[c * stride + t];
    s = fmaxf(s, 0.f);
#pragma unroll
    for (int m = 16; m >= 1; m >>= 1) s += __shfl_xor(s, m);
    if ((threadIdx.x & 31) == 0) rowsum[t >> 5] = s;
}

// ---------------------------------------------------------------------------
// K5: out[b][l] = sum_i s[b][i] * out_w[l][i] + out_b[l]
// ---------------------------------------------------------------------------
__global__ void final_linear(const float* __restrict__ s, const float* __restrict__ ow,
                             const float* __restrict__ ob, float* __restrict__ out) {
    const int l = blockIdx.x;
    const int b = blockIdx.y;
    const float* __restrict__ sr = s + (size_t)b * NN;
    const float* __restrict__ wr = ow + (size_t)l * NN;

    float acc = 0.f;
    for (int i = threadIdx.x; i < NN; i += 256) acc += sr[i] * wr[i];

#pragma unroll
    for (int off = 32; off > 0; off >>= 1) acc += __shfl_down(acc, off);

    __shared__ float red[4];
    if ((threadIdx.x & 63) == 0) red[threadIdx.x >> 6] = acc;
    __syncthreads();
    if (threadIdx.x == 0) {
        out[b * LL + l] = red[0] + red[1] + red[2] + red[3] + ob[l];
    }
}

// ---------------------------------------------------------------------------
extern "C" void kernel_launch(void* const* d_in, const int* in_sizes, int n_in,
                              void* d_out, int out_size, void* d_ws, size_t ws_size,
                              hipStream_t stream) {
    const float* v    = (const float*)d_in[0];  // (32, 2000, 32)
    const float* adj  = (const float*)d_in[1];  // (32, 2000, 2000)
    const float* W1   = (const float*)d_in[2];  // (32, 32)
    const float* W2   = (const float*)d_in[3];  // (32, 32)
    const float* outw = (const float*)d_in[4];  // (10, 2000)
    const float* outb = (const float*)d_in[5];  // (10,)
    float* out = (float*)d_out;                 // (32, 10)

    char* ws = (char*)d_ws;
    float* bufH = (float*)(ws);                      // 8 MB: h1 / h2
    float* bufY = (float*)(ws + (8u << 20));         // 8 MB: y1
    float* bufS = (float*)(ws + (16u << 20));        // 256 KB: rowsums
    float* partial = (float*)(ws + (17u << 20));     // JC * 8.19 MB

    const size_t partial_bytes_per_chunk = (size_t)BB * NN * FF * sizeof(float); // 8.192 MB
    const size_t base = 17u << 20;

    // Pick largest chunk count that (a) divides NN, (b) keeps chunks a
    // multiple of 4 (16B-aligned float4 stream), (c) fits the workspace.
    int JC = 1;
    const int cand[4] = {5, 4, 2, 1};
    for (int k = 0; k < 4; ++k) {
        if (base + (size_t)cand[k] * partial_bytes_per_chunk <= ws_size) { JC = cand[k]; break; }
    }
    const int chunk = NN / JC;

    const int rows = BB * NN;  // 64000

    // K1: h1 = v @ W1
    small_mm<<<dim3((rows * 32 + 255) / 256), dim3(256), 0, stream>>>(v, W1, bufH, rows);

    // L1: partial = adj @ h1 (j-split), then y1 = relu(reduce)
    gcn_partial<<<dim3((NN + 255) / 256, BB, JC), dim3(256), 0, stream>>>(adj, bufH, partial, chunk);
    reduce_relu<<<dim3(rows * FF / 256), dim3(256), 0, stream>>>(partial, bufY, JC);

    // K3: h2 = y1 @ W2
    small_mm<<<dim3((rows * 32 + 255) / 256), dim3(256), 0, stream>>>(bufY, W2, bufH, rows);

    // L2: partial = adj @ h2 (j-split), then s = rowsum(relu(reduce))
    gcn_partial<<<dim3((NN + 255) / 256, BB, JC), dim3(256), 0, stream>>>(adj, bufH, partial, chunk);
    reduce_relu_sum<<<dim3(rows * FF / 256), dim3(256), 0, stream>>>(partial, bufS, JC);

    // K5: out = s @ out_w.T + out_b
    final_linear<<<dim3(LL, BB), dim3(256), 0, stream>>>(bufS, outw, outb, out);
}

// Round 3
// 977.855 us; speedup vs baseline: 1.6226x; 1.6226x over previous
//
#include <hip/hip_runtime.h>
#include <hip/hip_bf16.h>

#define NN 2000
#define BB 32
#define FF 32
#define LL 10

// ---------------------------------------------------------------------------
// K1/K3: out(rows,32) = x(rows,32) @ w(32,32)
// ---------------------------------------------------------------------------
__global__ void small_mm(const float* __restrict__ x, const float* __restrict__ w,
                         float* __restrict__ out, int rows) {
    int t = blockIdx.x * blockDim.x + threadIdx.x;
    if (t >= rows * 32) return;
    int f = t & 31;
    int r = t >> 5;
    const float* xr = x + (size_t)r * 32;
    float acc = 0.f;
#pragma unroll
    for (int k = 0; k < 32; ++k) acc += xr[k] * w[k * 32 + f];
    out[t] = acc;
}

// ---------------------------------------------------------------------------
// gcn_tile: y[b][i][:] = relu(adj[b][i][:] @ h[b]) , optionally feature-summed.
//
// Block = 256 threads = 4 waves, covers 64 rows (lane l <-> row i0+l).
// Per 64-j stage:
//   - cooperative coalesced float4 load of adj[i0..i0+63][j0..j0+63] -> LDS
//     (stride 65 -> conflict-free b32 reads: bank = (l + c) % 32)
//   - wave w computes j-quarter [w*16, w*16+16): adj from LDS (lane-private),
//     h row from global via wave-uniform address (readfirstlane -> s_load
//     broadcast, hits scalar/L2 cache; h per batch = 256 KB, L2-resident).
// End: 4 per-wave partial acc[32] reduced through LDS; relu (+ feature-sum
// pool for layer 2) fused in the epilogue.
// ---------------------------------------------------------------------------
template <bool SUM_ONLY>
__global__ __launch_bounds__(256, 4)
void gcn_tile(const float* __restrict__ adj, const float* __restrict__ h,
              float* __restrict__ out, float* __restrict__ rowsum) {
    __shared__ float lds[4 * 64 * 33];   // 33.8 KB union: adj tile (64x65) / reduce (4x64x33)

    const int b  = blockIdx.y;
    const int i0 = blockIdx.x * 64;
    const int tid = threadIdx.x;
    const int w = tid >> 6;
    const int l = tid & 63;

    const float* __restrict__ hb = h + (size_t)b * NN * FF;
    const size_t adj_b = (size_t)b * NN;

    float acc[FF];
#pragma unroll
    for (int f = 0; f < FF; ++f) acc[f] = 0.f;

    for (int j0 = 0; j0 < NN; j0 += 64) {
        const int jcnt = (NN - j0 >= 64) ? 64 : (NN - j0);   // 64 or 16
        const int qs = (jcnt == 64) ? 4 : 2;                 // log2(jcnt/4)
        const int q = 1 << qs;                               // float4s per row

        __syncthreads();
        // stage adj tile (coalesced: consecutive lanes -> consecutive float4s)
        const int total = 64 << qs;
        for (int idx = tid; idx < total; idx += 256) {
            const int r = idx >> qs;
            const int c = idx & (q - 1);
            const int ri = (i0 + r < NN) ? (i0 + r) : (NN - 1);
            const float4 a = *reinterpret_cast<const float4*>(
                adj + (adj_b + ri) * NN + j0 + (c << 2));
            float* dst = lds + r * 65 + (c << 2);
            dst[0] = a.x; dst[1] = a.y; dst[2] = a.z; dst[3] = a.w;
        }
        __syncthreads();

        // compute: wave w handles jj in [w*jq, w*jq + jq)
        const int jq = jcnt >> 2;                             // 16 or 4
        const int wq = __builtin_amdgcn_readfirstlane(w * jq);
        const float* __restrict__ hp = hb + (size_t)(j0 + wq) * FF;
        const float* ap = lds + l * 65 + wq;
        for (int jj = 0; jj < jq; ++jj) {
            const float a = ap[jj];
            const float* __restrict__ hr = hp + jj * FF;
#pragma unroll
            for (int f = 0; f < FF; ++f) acc[f] += a * hr[f];
        }
    }

    // reduce the 4 per-wave partials through LDS
    __syncthreads();
    {
        float* dst = lds + (w * 64 + l) * 33;
#pragma unroll
        for (int f = 0; f < FF; ++f) dst[f] = acc[f];
    }
    __syncthreads();

    const int r = tid >> 2;            // 0..63
    const int f0 = (tid & 3) * 8;
    const int i = i0 + r;

    float vals[8];
#pragma unroll
    for (int k = 0; k < 8; ++k) {
        const int f = f0 + k;
        float s = lds[(0 * 64 + r) * 33 + f] + lds[(1 * 64 + r) * 33 + f]
                + lds[(2 * 64 + r) * 33 + f] + lds[(3 * 64 + r) * 33 + f];
        vals[k] = fmaxf(s, 0.f);
    }

    if (SUM_ONLY) {
        float s = 0.f;
#pragma unroll
        for (int k = 0; k < 8; ++k) s += vals[k];
        s += __shfl_xor(s, 1);
        s += __shfl_xor(s, 2);
        if ((tid & 3) == 0 && i < NN) rowsum[(size_t)b * NN + i] = s;
    } else {
        if (i < NN) {
            float* orow = out + ((size_t)b * NN + i) * FF + f0;
            *reinterpret_cast<float4*>(orow)     = make_float4(vals[0], vals[1], vals[2], vals[3]);
            *reinterpret_cast<float4*>(orow + 4) = make_float4(vals[4], vals[5], vals[6], vals[7]);
        }
    }
}

// ---------------------------------------------------------------------------
// K5: out[b][l] = sum_i s[b][i] * out_w[l][i] + out_b[l]
// ---------------------------------------------------------------------------
__global__ void final_linear(const float* __restrict__ s, const float* __restrict__ ow,
                             const float* __restrict__ ob, float* __restrict__ out) {
    const int l = blockIdx.x;
    const int b = blockIdx.y;
    const float* __restrict__ sr = s + (size_t)b * NN;
    const float* __restrict__ wr = ow + (size_t)l * NN;

    float acc = 0.f;
    for (int i = threadIdx.x; i < NN; i += 256) acc += sr[i] * wr[i];

#pragma unroll
    for (int off = 32; off > 0; off >>= 1) acc += __shfl_down(acc, off);

    __shared__ float red[4];
    if ((threadIdx.x & 63) == 0) red[threadIdx.x >> 6] = acc;
    __syncthreads();
    if (threadIdx.x == 0) {
        out[b * LL + l] = red[0] + red[1] + red[2] + red[3] + ob[l];
    }
}

// ---------------------------------------------------------------------------
extern "C" void kernel_launch(void* const* d_in, const int* in_sizes, int n_in,
                              void* d_out, int out_size, void* d_ws, size_t ws_size,
                              hipStream_t stream) {
    const float* v    = (const float*)d_in[0];  // (32, 2000, 32)
    const float* adj  = (const float*)d_in[1];  // (32, 2000, 2000)
    const float* W1   = (const float*)d_in[2];  // (32, 32)
    const float* W2   = (const float*)d_in[3];  // (32, 32)
    const float* outw = (const float*)d_in[4];  // (10, 2000)
    const float* outb = (const float*)d_in[5];  // (10,)
    float* out = (float*)d_out;                 // (32, 10)

    char* ws = (char*)d_ws;
    float* bufH = (float*)(ws);                  // 8 MB: h1 / h2
    float* bufY = (float*)(ws + (8u << 20));     // 8 MB: y1
    float* bufS = (float*)(ws + (16u << 20));    // 256 KB: rowsums

    const int rows = BB * NN;  // 64000
    const dim3 gcn_grid((NN + 63) / 64, BB);     // 32 x 32 = 1024 blocks

    // K1: h1 = v @ W1
    small_mm<<<dim3((rows * 32 + 255) / 256), dim3(256), 0, stream>>>(v, W1, bufH, rows);

    // K2: y1 = relu(adj @ h1)
    gcn_tile<false><<<gcn_grid, dim3(256), 0, stream>>>(adj, bufH, bufY, nullptr);

    // K3: h2 = y1 @ W2
    small_mm<<<dim3((rows * 32 + 255) / 256), dim3(256), 0, stream>>>(bufY, W2, bufH, rows);

    // K4: s = sum_f relu(adj @ h2)
    gcn_tile<true><<<gcn_grid, dim3(256), 0, stream>>>(adj, bufH, nullptr, bufS);

    // K5: out = s @ out_w.T + out_b
    final_linear<<<dim3(LL, BB), dim3(256), 0, stream>>>(bufS, outw, outb, out);
}